// Round 14
// baseline (1998.091 us; speedup 1.0000x reference)
//
#include <hip/hip_runtime.h>
#include <stdint.h>

#define TAGS 29
#define START_TAG 27
#define STOP_TAG 28
#define BB 64
#define LL 1024
#define DD 1024
#define HH 512
#define FSTRIDE 32   // padded feats row stride (floats)

typedef float f2 __attribute__((ext_vector_type(2)));
struct f4view { f2 lo, hi; };

// ---------------------------------------------------------------------------
// Tied VOP3P MAC: acc += broadcast(aPair[SEL]) * b. 2 VALU instrs, no movs.
// v_pk lanes are independent IEEE f32 (same rounding as v_mul/v_add) ->
// bit-identical to scalar mul-then-add. PROVEN r11/r13 (absmax=0).
// ---------------------------------------------------------------------------
template <int SEL>
__device__ __forceinline__ void pk_mac(f2& acc, f2 aPair, f2 b) {
  f2 t;
  if constexpr (SEL == 0)
    asm("v_pk_mul_f32 %0, %2, %3 op_sel:[0,0] op_sel_hi:[0,1]\n\t"
        "v_pk_add_f32 %1, %1, %0"
        : "=&v"(t), "+v"(acc) : "v"(aPair), "v"(b));
  else
    asm("v_pk_mul_f32 %0, %2, %3 op_sel:[1,0] op_sel_hi:[1,1]\n\t"
        "v_pk_add_f32 %1, %1, %0"
        : "=&v"(t), "+v"(acc) : "v"(aPair), "v"(b));
}

// ---------------------------------------------------------------------------
// XLA EmitFastTanh clone, f32, with_fma=false. PROVEN bit-exact (r3..r13).
// ---------------------------------------------------------------------------
__device__ __forceinline__ float xla_tanh_f32(float x) {
#pragma clang fp contract(off)
  const float kMax = 7.90531110763549805f;
  float xc = fminf(fmaxf(x, -kMax), kMax);
  float x2 = xc * xc;
  float p = x2 * -2.76076847742355e-16f + 2.00018790482477e-13f;
  p = x2 * p + -8.60467152213735e-11f;
  p = x2 * p + 5.12229709037114e-08f;
  p = x2 * p + 1.48572235717979e-05f;
  p = x2 * p + 6.37261928875436e-04f;
  p = x2 * p + 4.89352455891786e-03f;
  p = xc * p;
  float q = x2 * 1.19825839466702e-06f + 1.18534705686654e-04f;
  q = x2 * q + 2.26843463243900e-03f;
  q = x2 * q + 4.89352518554385e-03f;
  float r = p / q;                       // IEEE div
  return (fabsf(x) < 4.0e-4f) ? x : r;
}

// ---------------------------------------------------------------------------
// Async global->LDS staging of one K-tile (kb..kb+7). Zero staging VGPRs.
// buf floats: [0..511]     xs = X[row0..row0+63][kb..kb+7], row-major [64][8]
//             [512..4607]  wl = W1[kb..kb+7][0..511],       row-major [8][512]
// Dest = wave-uniform base + lane*16 (HW rule); both layouts linear:
//   X: tid<128, dest byte tid*16 -> row tid>>1, colq tid&1 (per-lane src)
//   W: all 512 threads, m=0..1: dest 2048 + m*8192 + tid*16 (flat 16 KB copy)
// ---------------------------------------------------------------------------
__device__ __forceinline__ void stage_tile(const float* __restrict__ X,
                                           const float* __restrict__ W1,
                                           float* buf, int row0, int kb, int tid) {
  const int wid = tid >> 6;
  if (tid < 128) {
    const float* src = X + (size_t)(row0 + (tid >> 1)) * DD + kb + (tid & 1) * 4;
    __builtin_amdgcn_global_load_lds(
        (const __attribute__((address_space(1))) void*)src,
        (__attribute__((address_space(3))) void*)((char*)buf + wid * 1024),
        16, 0, 0);
  }
#pragma unroll
  for (int m = 0; m < 2; ++m) {
    const float* src = W1 + (size_t)kb * HH + m * 2048 + tid * 4;
    __builtin_amdgcn_global_load_lds(
        (const __attribute__((address_space(1))) void*)src,
        (__attribute__((address_space(3))) void*)((char*)buf + 2048 + m * 8192 + wid * 1024),
        16, 0, 0);
  }
}

// ---------------------------------------------------------------------------
// Kernel 1: fused MLP  feats = tanh(X@W1 + b1) @ W2 + b2
// 512 threads, 64x512 tile, 8x8 per thread (r13-proven inner loop).
// NEW vs r13: K-tile 8 -> double-buffer LDS 36864 B -> 4 blocks/CU
// (was 2): cross-block TLP buries the vmcnt(0)-before-barrier drain that
// was the 18% stall. Epilogue becomes 4 phases of 128 cols (hs[64][132])
// with the k-sum carried across ascending phases -> same k-ascending
// accumulation order, feats bit-identical.
// ---------------------------------------------------------------------------
__global__ __launch_bounds__(512)
__attribute__((amdgpu_waves_per_eu(4, 8)))
void mlp_kernel(
    const float* __restrict__ X, const float* __restrict__ W1,
    const float* __restrict__ b1, const float* __restrict__ W2,
    const float* __restrict__ b2, float* __restrict__ feats)
{
#pragma clang fp contract(off)
  __shared__ __align__(16) float smem[9216];    // 2 x 4608 floats = 36864 B
  float* hs = smem;                             // [64][132] epilogue overlay

  const int tid  = threadIdx.x;
  const int row0 = blockIdx.x * 64;
  const int rg = tid >> 6;        // wave id 0..7 -> rows rg*8..rg*8+7
  const int cg = tid & 63;        // cols {cg*4..+3} u {256+cg*4..+3}

  f2 acc[8][4];                   // 8 rows x (4+4 packed cols) = 64 VGPR
#pragma unroll
  for (int i = 0; i < 8; ++i)
#pragma unroll
    for (int j = 0; j < 4; ++j) acc[i][j] = (f2)(0.f);

  stage_tile(X, W1, smem, row0, 0, tid);
  __syncthreads();                // drains vmcnt: tile 0 ready

  for (int kt = 0; kt < 128; ++kt) {
    const int cur = kt & 1;
    if (kt + 1 < 128)             // next tile's loads fly under compute
      stage_tile(X, W1, smem + (cur ^ 1) * 4608, row0, (kt + 1) * 8, tid);

    const float* xsb = smem + cur * 4608;       // [64][8]
    const float* wlb = xsb + 512;               // [8][512]
#pragma unroll
    for (int kk4 = 0; kk4 < 2; ++kk4) {
      float4 a4[8];
#pragma unroll
      for (int i = 0; i < 8; ++i)               // broadcast reads (rg uniform)
        a4[i] = *(const float4*)(xsb + (rg * 8 + i) * 8 + kk4 * 4);
#pragma unroll
      for (int dk = 0; dk < 4; ++dk) {
        const int k = kk4 * 4 + dk;
        float4 b0  = *(const float4*)(wlb + k * HH + cg * 4);        // contig b128
        float4 b1v = *(const float4*)(wlb + k * HH + 256 + cg * 4);  // contig b128
        f4view bva = __builtin_bit_cast(f4view, b0);
        f4view bvb = __builtin_bit_cast(f4view, b1v);
        f2 bv[4] = {bva.lo, bva.hi, bvb.lo, bvb.hi};
#pragma unroll
        for (int i = 0; i < 8; ++i) {
          f4view av = __builtin_bit_cast(f4view, a4[i]);
          f2 ap = (dk < 2) ? av.lo : av.hi;     // pair holding k's scalar
#pragma unroll
          for (int j = 0; j < 4; ++j) {
            if (dk & 1) pk_mac<1>(acc[i][j], ap, bv[j]);
            else        pk_mac<0>(acc[i][j], ap, bv[j]);
          }
        }
      }
    }
    __syncthreads();  // buf[cur] reads done; staged loads drained
  }

  // ---- epilogue: 4 phases of 128 h-cols; k-sum carried across phases ----
  // phase p: global h cols [p*128, p*128+128). Writers: cg<32 for even p,
  // cg>=32 for odd p; acc half A (j=0,1) for p<2, half B (j=2,3) for p>=2.
  float sum4[4] = {0.f, 0.f, 0.f, 0.f};

#pragma unroll
  for (int p = 0; p < 4; ++p) {
    const int accb = (p >> 1) * 2;              // 0 or 2
    const bool hi = (p & 1);                    // writer half
    if ((cg >= 32) == hi) {
      const int lc0 = (cg & 31) * 4;            // local col 0..127
      const int gc0 = p * 128 + lc0;            // global col (b1 index)
#pragma unroll
      for (int i = 0; i < 8; ++i) {
        int r = rg * 8 + i;
        float4 hv;
        hv.x = xla_tanh_f32(acc[i][accb + 0].x + b1[gc0 + 0]);
        hv.y = xla_tanh_f32(acc[i][accb + 0].y + b1[gc0 + 1]);
        hv.z = xla_tanh_f32(acc[i][accb + 1].x + b1[gc0 + 2]);
        hv.w = xla_tanh_f32(acc[i][accb + 1].y + b1[gc0 + 3]);
        *(float4*)(hs + r * 132 + lc0) = hv;
      }
    }
    __syncthreads();
#pragma unroll
    for (int it = 0; it < 4; ++it) {
      int idx = tid + it * 512;
      if (idx < 64 * TAGS) {
        int r = idx & 63, c = idx >> 6;         // c wave-uniform -> W2 scalar
        float s = sum4[it];
#pragma unroll 4
        for (int k4 = 0; k4 < 32; ++k4) {
          float4 h4 = *(float4*)(hs + r * 132 + k4 * 4);
          float p0 = h4.x * W2[(p * 128 + k4 * 4 + 0) * TAGS + c]; s = s + p0;
          float p1 = h4.y * W2[(p * 128 + k4 * 4 + 1) * TAGS + c]; s = s + p1;
          float p2 = h4.z * W2[(p * 128 + k4 * 4 + 2) * TAGS + c]; s = s + p2;
          float p3 = h4.w * W2[(p * 128 + k4 * 4 + 3) * TAGS + c]; s = s + p3;
        }
        sum4[it] = s;
        if (p == 3)
          feats[(size_t)(row0 + r) * FSTRIDE + c] = s + b2[c];
      }
    }
    if (p < 3) __syncthreads();   // hs reads done before next phase's writes
  }
}

// ---------------------------------------------------------------------------
// Kernel 2: top-1 Viterbi — BYTE-FOR-BYTE the r9..r13 kernel (passed,
// absmax=0). DO NOT TOUCH.
// ---------------------------------------------------------------------------
__global__ __launch_bounds__(64)
__attribute__((amdgpu_waves_per_eu(1, 4)))
void viterbi_kernel(
    const float* __restrict__ feats, const float* __restrict__ trans,
    int* __restrict__ out)
{
#pragma clang fp contract(off)
  const int b = blockIdx.x;
  const int lane = threadIdx.x;
  const bool act = lane < TAGS;
  __shared__ unsigned char bp[LL][32];       // 32 KB back-pointers
  __shared__ __align__(16) float em[2048];   // 8 KB: 64 steps x 32 tags
  __shared__ __align__(16) float pbuf[32];

  float tr[TAGS];
  const int tl = act ? lane : 0;
#pragma unroll
  for (int f = 0; f < TAGS; ++f) tr[f] = trans[f * TAGS + tl];

  const float* frow = feats + (size_t)b * LL * FSTRIDE;
  float part = act ? (frow[lane] + tr[START_TAG]) : -3.0e38f;
  if (lane >= TAGS && lane < 32) pbuf[lane] = -3.0e38f;   // pad slots, once

  for (int tc = 0; tc < LL / 64; ++tc) {
    {
      const float* flat = frow + tc * 2048;
#pragma unroll
      for (int i = 0; i < 8; ++i) {
        float4 v4 = *(const float4*)(flat + lane * 4 + i * 256);
        *(float4*)(em + lane * 4 + i * 256) = v4;
      }
    }
    const int t0c = (tc == 0) ? 1 : tc * 64;
    const int t1c = tc * 64 + 64;
    for (int t = t0c; t < t1c; ++t) {
      float fv = em[((t & 63) << 5) + lane];
      if (act) pbuf[lane] = part;              // same-wave LDS: in-order
      const float4* pq = (const float4*)pbuf;
      float bvv = -3.0e38f;
      int bii = 0;
#pragma unroll
      for (int cch = 0; cch < 4; ++cch) {
        float4 sA = pq[cch * 2 + 0];
        float4 sB = pq[cch * 2 + 1];
        float s8[8] = {sA.x, sA.y, sA.z, sA.w, sB.x, sB.y, sB.z, sB.w};
        float v8[8];
#pragma unroll
        for (int j = 0; j < 8; ++j) {
          int fr = cch * 8 + j;
          v8[j] = (fr < TAGS) ? ((fv + tr[fr]) + s8[j]) : -3.0e38f;
        }
        float t4[4]; int i4[4];
#pragma unroll
        for (int i = 0; i < 4; ++i) { bool w = v8[2*i+1] > v8[2*i];
          t4[i] = w ? v8[2*i+1] : v8[2*i]; i4[i] = w ? 2*i+1 : 2*i; }
        float t2[2]; int i2[2];
#pragma unroll
        for (int i = 0; i < 2; ++i) { bool w = t4[2*i+1] > t4[2*i];
          t2[i] = w ? t4[2*i+1] : t4[2*i]; i2[i] = w ? i4[2*i+1] : i4[2*i]; }
        bool w = t2[1] > t2[0];
        float cv = w ? t2[1] : t2[0];
        int   ci = (w ? i2[1] : i2[0]) + cch * 8;
        if (cv > bvv) { bvv = cv; bii = ci; }
      }
      part = bvv;
      if (act) bp[t][lane] = (unsigned char)bii;
    }
  }

  float best = -3.0e38f;
  int p0 = 0;
#pragma unroll
  for (int fr = 0; fr < TAGS; ++fr) {
    float s = __shfl(part, fr, 64);
    float v = s + trans[fr * TAGS + STOP_TAG];
    if (v > best) { best = v; p0 = fr; }
  }

  __syncthreads();
  if (lane == 0) {
    int* ob = out + (size_t)b * LL;
    int p = p0;
    ob[LL - 1] = p;
    for (int t = LL - 1; t >= 1; --t) {
      p = bp[t][p];
      ob[t - 1] = p;
    }
  }
}

// ---------------------------------------------------------------------------
extern "C" void kernel_launch(void* const* d_in, const int* in_sizes, int n_in,
                              void* d_out, int out_size, void* d_ws, size_t ws_size,
                              hipStream_t stream) {
  const float* X  = (const float*)d_in[0];
  const float* W1 = (const float*)d_in[2];
  const float* b1 = (const float*)d_in[3];
  const float* W2 = (const float*)d_in[4];
  const float* b2 = (const float*)d_in[5];
  const float* tr = (const float*)d_in[6];

  float* feats = (float*)d_ws;          // (B*L) x 32 padded fp32 rows = 8 MB
  int* out = (int*)d_out;

  mlp_kernel<<<dim3(BB * LL / 64), dim3(512), 0, stream>>>(X, W1, b1, W2, b2, feats);
  viterbi_kernel<<<dim3(BB), dim3(64), 0, stream>>>(feats, tr, out);
}

// Round 15
// 1858.413 us; speedup vs baseline: 1.0752x; 1.0752x over previous
//
#include <hip/hip_runtime.h>
#include <stdint.h>

#define TAGS 29
#define START_TAG 27
#define STOP_TAG 28
#define BB 64
#define LL 1024
#define DD 1024
#define HH 512
#define FSTRIDE 32   // padded feats row stride (floats)

typedef float f2 __attribute__((ext_vector_type(2)));
struct f4view { f2 lo, hi; };

// ---------------------------------------------------------------------------
// Tied VOP3P MAC: acc += broadcast(aPair[SEL]) * b. 2 VALU instrs, no movs.
// v_pk lanes are independent IEEE f32 (same rounding as v_mul/v_add) ->
// bit-identical to scalar mul-then-add. PROVEN r11/r13 (absmax=0).
// ---------------------------------------------------------------------------
template <int SEL>
__device__ __forceinline__ void pk_mac(f2& acc, f2 aPair, f2 b) {
  f2 t;
  if constexpr (SEL == 0)
    asm("v_pk_mul_f32 %0, %2, %3 op_sel:[0,0] op_sel_hi:[0,1]\n\t"
        "v_pk_add_f32 %1, %1, %0"
        : "=&v"(t), "+v"(acc) : "v"(aPair), "v"(b));
  else
    asm("v_pk_mul_f32 %0, %2, %3 op_sel:[1,0] op_sel_hi:[1,1]\n\t"
        "v_pk_add_f32 %1, %1, %0"
        : "=&v"(t), "+v"(acc) : "v"(aPair), "v"(b));
}

// ---------------------------------------------------------------------------
// XLA EmitFastTanh clone, f32, with_fma=false. PROVEN bit-exact (r3..r13).
// ---------------------------------------------------------------------------
__device__ __forceinline__ float xla_tanh_f32(float x) {
#pragma clang fp contract(off)
  const float kMax = 7.90531110763549805f;
  float xc = fminf(fmaxf(x, -kMax), kMax);
  float x2 = xc * xc;
  float p = x2 * -2.76076847742355e-16f + 2.00018790482477e-13f;
  p = x2 * p + -8.60467152213735e-11f;
  p = x2 * p + 5.12229709037114e-08f;
  p = x2 * p + 1.48572235717979e-05f;
  p = x2 * p + 6.37261928875436e-04f;
  p = x2 * p + 4.89352455891786e-03f;
  p = xc * p;
  float q = x2 * 1.19825839466702e-06f + 1.18534705686654e-04f;
  q = x2 * q + 2.26843463243900e-03f;
  q = x2 * q + 4.89352518554385e-03f;
  float r = p / q;                       // IEEE div
  return (fabsf(x) < 4.0e-4f) ? x : r;
}

// ---------------------------------------------------------------------------
// Async global->LDS staging of one K-tile (kb..kb+15). Zero staging VGPRs.
// buf floats: [0..1023]     xs = X[row0..row0+63][kb..kb+15], row-major [64][16]
//             [1024..9215]  wl = W1[kb..kb+15][0..511],       row-major [16][512]
// Dest = wave-uniform base + lane*16 (HW rule); both layouts linear.
//   X: threads 0..255, dest byte t*16  -> row t>>2, colq t&3 (per-lane src)
//   W: all 512 threads, m=0..3: dest 4096 + m*8192 + t*16 (flat 32 KB copy)
// ---------------------------------------------------------------------------
__device__ __forceinline__ void stage_tile(const float* __restrict__ X,
                                           const float* __restrict__ W1,
                                           float* buf, int row0, int kb, int tid) {
  const int wid = tid >> 6;
  if (tid < 256) {
    const float* src = X + (size_t)(row0 + (tid >> 2)) * DD + kb + (tid & 3) * 4;
    __builtin_amdgcn_global_load_lds(
        (const __attribute__((address_space(1))) void*)src,
        (__attribute__((address_space(3))) void*)((char*)buf + wid * 1024),
        16, 0, 0);
  }
#pragma unroll
  for (int m = 0; m < 4; ++m) {
    const float* src = W1 + (size_t)kb * HH + m * 2048 + tid * 4;
    __builtin_amdgcn_global_load_lds(
        (const __attribute__((address_space(1))) void*)src,
        (__attribute__((address_space(3))) void*)((char*)buf + 4096 + m * 8192 + wid * 1024),
        16, 0, 0);
  }
}

// ---------------------------------------------------------------------------
// Kernel 1: fused MLP  feats = tanh(X@W1 + b1) @ W2 + b2
// 512 threads (8 waves), 64 rows x 512 cols/block, 8 rows x 8 cols/thread.
// K-tile 16, double-buffered gload_lds, 72 KB LDS -> 2 blocks/CU.
// BEST-KNOWN CONFIG (r13: mlp 1405 us, total 1792, absmax=0). The r14
// kt=8/4-phase experiment regressed (occupancy unchanged, 2x barriers,
// epilogue bank conflicts) and is reverted.
// Numerics: per-output k-ascending mul-round/add-round chain; pk lanes
// independent IEEE f32 -> feats bit-identical to reference.
// ---------------------------------------------------------------------------
__global__ __launch_bounds__(512)
__attribute__((amdgpu_waves_per_eu(4, 8)))
void mlp_kernel(
    const float* __restrict__ X, const float* __restrict__ W1,
    const float* __restrict__ b1, const float* __restrict__ W2,
    const float* __restrict__ b2, float* __restrict__ feats)
{
#pragma clang fp contract(off)
  __shared__ __align__(16) float smem[18432];   // 2 x 9216 floats = 73728 B
  float* hs = smem;                             // [64][260] epilogue overlay

  const int tid  = threadIdx.x;
  const int row0 = blockIdx.x * 64;
  const int rg = tid >> 6;        // wave id 0..7 -> rows rg*8..rg*8+7
  const int cg = tid & 63;        // cols {cg*4..+3} u {256+cg*4..+3}

  f2 acc[8][4];                   // 8 rows x (4+4 packed cols) = 64 VGPR
#pragma unroll
  for (int i = 0; i < 8; ++i)
#pragma unroll
    for (int j = 0; j < 4; ++j) acc[i][j] = (f2)(0.f);

  stage_tile(X, W1, smem, row0, 0, tid);
  __syncthreads();                // compiler drains vmcnt before barrier

  for (int kt = 0; kt < 64; ++kt) {
    const int cur = kt & 1;
    if (kt + 1 < 64)              // next tile's loads fly under compute
      stage_tile(X, W1, smem + (cur ^ 1) * 9216, row0, (kt + 1) * 16, tid);

    const float* xsb = smem + cur * 9216;       // [64][16]
    const float* wlb = xsb + 1024;              // [16][512]
#pragma unroll
    for (int kk4 = 0; kk4 < 4; ++kk4) {
      float4 a4[8];
#pragma unroll
      for (int i = 0; i < 8; ++i)               // broadcast reads (rg uniform)
        a4[i] = *(const float4*)(xsb + (rg * 8 + i) * 16 + kk4 * 4);
#pragma unroll
      for (int dk = 0; dk < 4; ++dk) {
        const int k = kk4 * 4 + dk;
        float4 b0  = *(const float4*)(wlb + k * HH + cg * 4);        // contig b128
        float4 b1v = *(const float4*)(wlb + k * HH + 256 + cg * 4);  // contig b128
        f4view bva = __builtin_bit_cast(f4view, b0);
        f4view bvb = __builtin_bit_cast(f4view, b1v);
        f2 bv[4] = {bva.lo, bva.hi, bvb.lo, bvb.hi};
#pragma unroll
        for (int i = 0; i < 8; ++i) {
          f4view av = __builtin_bit_cast(f4view, a4[i]);
          f2 ap = (dk < 2) ? av.lo : av.hi;     // pair holding k's scalar
#pragma unroll
          for (int j = 0; j < 4; ++j) {
            if (dk & 1) pk_mac<1>(acc[i][j], ap, bv[j]);
            else        pk_mac<0>(acc[i][j], ap, bv[j]);
          }
        }
      }
    }
    __syncthreads();  // buf[cur] reads done; staged loads drained
  }

  float sum[4] = {0.f, 0.f, 0.f, 0.f};

  // ---- phase A: h cols 0..255 ----  (hs overlays buf0; safe after barrier)
  {
    const int c0 = cg * 4;
#pragma unroll
    for (int i = 0; i < 8; ++i) {
      int r = rg * 8 + i;
      float4 hv;
      hv.x = xla_tanh_f32(acc[i][0].x + b1[c0 + 0]);
      hv.y = xla_tanh_f32(acc[i][0].y + b1[c0 + 1]);
      hv.z = xla_tanh_f32(acc[i][1].x + b1[c0 + 2]);
      hv.w = xla_tanh_f32(acc[i][1].y + b1[c0 + 3]);
      *(float4*)(hs + r * 260 + c0) = hv;
    }
  }
  __syncthreads();
#pragma unroll
  for (int it = 0; it < 4; ++it) {
    int idx = tid + it * 512;
    if (idx < 64 * TAGS) {
      int r = idx & 63, c = idx >> 6;        // c wave-uniform -> W2 scalarizes
      float s = 0.f;
#pragma unroll 4
      for (int k4 = 0; k4 < 64; ++k4) {
        float4 h4 = *(float4*)(hs + r * 260 + k4 * 4);
        float p0 = h4.x * W2[(k4 * 4 + 0) * TAGS + c]; s = s + p0;
        float p1 = h4.y * W2[(k4 * 4 + 1) * TAGS + c]; s = s + p1;
        float p2 = h4.z * W2[(k4 * 4 + 2) * TAGS + c]; s = s + p2;
        float p3 = h4.w * W2[(k4 * 4 + 3) * TAGS + c]; s = s + p3;
      }
      sum[it] = s;
    }
  }
  __syncthreads();

  // ---- phase B: h cols 256..511 ----
  {
    const int c0 = cg * 4;
#pragma unroll
    for (int i = 0; i < 8; ++i) {
      int r = rg * 8 + i;
      float4 hv;
      hv.x = xla_tanh_f32(acc[i][2].x + b1[256 + c0 + 0]);
      hv.y = xla_tanh_f32(acc[i][2].y + b1[256 + c0 + 1]);
      hv.z = xla_tanh_f32(acc[i][3].x + b1[256 + c0 + 2]);
      hv.w = xla_tanh_f32(acc[i][3].y + b1[256 + c0 + 3]);
      *(float4*)(hs + r * 260 + c0) = hv;
    }
  }
  __syncthreads();
#pragma unroll
  for (int it = 0; it < 4; ++it) {
    int idx = tid + it * 512;
    if (idx < 64 * TAGS) {
      int r = idx & 63, c = idx >> 6;
      float s = sum[it];
#pragma unroll 4
      for (int k4 = 0; k4 < 64; ++k4) {
        float4 h4 = *(float4*)(hs + r * 260 + k4 * 4);
        float p0 = h4.x * W2[(256 + k4 * 4 + 0) * TAGS + c]; s = s + p0;
        float p1 = h4.y * W2[(256 + k4 * 4 + 1) * TAGS + c]; s = s + p1;
        float p2 = h4.z * W2[(256 + k4 * 4 + 2) * TAGS + c]; s = s + p2;
        float p3 = h4.w * W2[(256 + k4 * 4 + 3) * TAGS + c]; s = s + p3;
      }
      feats[(size_t)(row0 + r) * FSTRIDE + c] = s + b2[c];
    }
  }
}

// ---------------------------------------------------------------------------
// Kernel 2: top-1 Viterbi — BYTE-FOR-BYTE the r9..r13 kernel (passed,
// absmax=0). DO NOT TOUCH.
// ---------------------------------------------------------------------------
__global__ __launch_bounds__(64)
__attribute__((amdgpu_waves_per_eu(1, 4)))
void viterbi_kernel(
    const float* __restrict__ feats, const float* __restrict__ trans,
    int* __restrict__ out)
{
#pragma clang fp contract(off)
  const int b = blockIdx.x;
  const int lane = threadIdx.x;
  const bool act = lane < TAGS;
  __shared__ unsigned char bp[LL][32];       // 32 KB back-pointers
  __shared__ __align__(16) float em[2048];   // 8 KB: 64 steps x 32 tags
  __shared__ __align__(16) float pbuf[32];

  float tr[TAGS];
  const int tl = act ? lane : 0;
#pragma unroll
  for (int f = 0; f < TAGS; ++f) tr[f] = trans[f * TAGS + tl];

  const float* frow = feats + (size_t)b * LL * FSTRIDE;
  float part = act ? (frow[lane] + tr[START_TAG]) : -3.0e38f;
  if (lane >= TAGS && lane < 32) pbuf[lane] = -3.0e38f;   // pad slots, once

  for (int tc = 0; tc < LL / 64; ++tc) {
    {
      const float* flat = frow + tc * 2048;
#pragma unroll
      for (int i = 0; i < 8; ++i) {
        float4 v4 = *(const float4*)(flat + lane * 4 + i * 256);
        *(float4*)(em + lane * 4 + i * 256) = v4;
      }
    }
    const int t0c = (tc == 0) ? 1 : tc * 64;
    const int t1c = tc * 64 + 64;
    for (int t = t0c; t < t1c; ++t) {
      float fv = em[((t & 63) << 5) + lane];
      if (act) pbuf[lane] = part;              // same-wave LDS: in-order
      const float4* pq = (const float4*)pbuf;
      float bvv = -3.0e38f;
      int bii = 0;
#pragma unroll
      for (int cch = 0; cch < 4; ++cch) {
        float4 sA = pq[cch * 2 + 0];
        float4 sB = pq[cch * 2 + 1];
        float s8[8] = {sA.x, sA.y, sA.z, sA.w, sB.x, sB.y, sB.z, sB.w};
        float v8[8];
#pragma unroll
        for (int j = 0; j < 8; ++j) {
          int fr = cch * 8 + j;
          v8[j] = (fr < TAGS) ? ((fv + tr[fr]) + s8[j]) : -3.0e38f;
        }
        float t4[4]; int i4[4];
#pragma unroll
        for (int i = 0; i < 4; ++i) { bool w = v8[2*i+1] > v8[2*i];
          t4[i] = w ? v8[2*i+1] : v8[2*i]; i4[i] = w ? 2*i+1 : 2*i; }
        float t2[2]; int i2[2];
#pragma unroll
        for (int i = 0; i < 2; ++i) { bool w = t4[2*i+1] > t4[2*i];
          t2[i] = w ? t4[2*i+1] : t4[2*i]; i2[i] = w ? i4[2*i+1] : i4[2*i]; }
        bool w = t2[1] > t2[0];
        float cv = w ? t2[1] : t2[0];
        int   ci = (w ? i2[1] : i2[0]) + cch * 8;
        if (cv > bvv) { bvv = cv; bii = ci; }
      }
      part = bvv;
      if (act) bp[t][lane] = (unsigned char)bii;
    }
  }

  float best = -3.0e38f;
  int p0 = 0;
#pragma unroll
  for (int fr = 0; fr < TAGS; ++fr) {
    float s = __shfl(part, fr, 64);
    float v = s + trans[fr * TAGS + STOP_TAG];
    if (v > best) { best = v; p0 = fr; }
  }

  __syncthreads();
  if (lane == 0) {
    int* ob = out + (size_t)b * LL;
    int p = p0;
    ob[LL - 1] = p;
    for (int t = LL - 1; t >= 1; --t) {
      p = bp[t][p];
      ob[t - 1] = p;
    }
  }
}

// ---------------------------------------------------------------------------
extern "C" void kernel_launch(void* const* d_in, const int* in_sizes, int n_in,
                              void* d_out, int out_size, void* d_ws, size_t ws_size,
                              hipStream_t stream) {
  const float* X  = (const float*)d_in[0];
  const float* W1 = (const float*)d_in[2];
  const float* b1 = (const float*)d_in[3];
  const float* W2 = (const float*)d_in[4];
  const float* b2 = (const float*)d_in[5];
  const float* tr = (const float*)d_in[6];

  float* feats = (float*)d_ws;          // (B*L) x 32 padded fp32 rows = 8 MB
  int* out = (int*)d_out;

  mlp_kernel<<<dim3(BB * LL / 64), dim3(512), 0, stream>>>(X, W1, b1, W2, b2, feats);
  viterbi_kernel<<<dim3(BB), dim3(64), 0, stream>>>(feats, tr, out);
}